// Round 4
// baseline (361.831 us; speedup 1.0000x reference)
//
#include <hip/hip_runtime.h>

#define HH 128
#define WW 128
#define CC 64
// LSTR=84: (1) pads LDS rows so b128 reads spread over all 32 banks;
// (2) total LDS = 2*128*84*4 = 86016 B > 80 KB, so only ONE 1024-thread
// block fits per CU (2 blocks would need 168 KB > 160 KB). This pins the
// compiler's occupancy-driven RA target to 4 waves/EU -> 128-VGPR budget.
// With LSTR=68 (69632 B, 2 blocks/CU possible) the RA targeted 8 waves/EU,
// capped at 64 VGPRs, and spilled ~35 floats/thread (+272 MB HBM writes).
#define LSTR 84
#define BS 1024
#define DTC 0.2f

// workspace float offsets (folded params written by fold_params pre-kernel)
#define OFF_WG   0
#define OFF_WG1  576
#define OFF_WDX  1152
#define OFF_WDY  1728
#define OFF_BIAS 2304    // [4][64]
#define OFF_SO   2560
#define OFF_BO   2624
#define WS_FLOATS 2688

struct F8 { float4 lo, hi; };

__device__ __forceinline__ F8 ld8(const float* p) {
    F8 r; r.lo = *(const float4*)p; r.hi = *(const float4*)(p + 4); return r;
}
__device__ __forceinline__ void st8(float* p, const F8& v) {
    *(float4*)p = v.lo; *(float4*)(p + 4) = v.hi;
}
__device__ __forceinline__ F8 zero8() {
    F8 r; r.lo = make_float4(0.f,0.f,0.f,0.f); r.hi = r.lo; return r;
}

#define F8_ALL(X) X(lo.x) X(lo.y) X(lo.z) X(lo.w) X(hi.x) X(hi.y) X(hi.z) X(hi.w)

__device__ __forceinline__ void fma8(F8& a, const F8& v, const F8& w) {
#define X(f) a.f = fmaf(v.f, w.f, a.f);
    F8_ALL(X)
#undef X
}
__device__ __forceinline__ F8 relu8(const F8& v) {
    F8 r;
#define X(f) r.f = fmaxf(v.f, 0.f);
    F8_ALL(X)
#undef X
    return r;
}
__device__ __forceinline__ F8 scale8(const F8& v, float s) {
    F8 r;
#define X(f) r.f = v.f * s;
    F8_ALL(X)
#undef X
    return r;
}
// result[i] = v[i-1]; result[0] = edge  (channel roll +1)
__device__ __forceinline__ F8 shr8(const F8& v, float edge) {
    F8 r;
    r.lo.x = edge;   r.lo.y = v.lo.x; r.lo.z = v.lo.y; r.lo.w = v.lo.z;
    r.hi.x = v.lo.w; r.hi.y = v.hi.x; r.hi.z = v.hi.y; r.hi.w = v.hi.z;
    return r;
}
// result[i] = v[i+1]; result[7] = edge  (channel roll -1)
__device__ __forceinline__ F8 shl8(const F8& v, float edge) {
    F8 r;
    r.lo.x = v.lo.y; r.lo.y = v.lo.z; r.lo.z = v.lo.w; r.lo.w = v.hi.x;
    r.hi.x = v.hi.y; r.hi.y = v.hi.z; r.hi.z = v.hi.w; r.hi.w = edge;
    return r;
}

// ---------------- pre-kernel: fold BN into conv weights -------------------
__global__ void fold_params(const float* __restrict__ kg,  const float* __restrict__ kg1,
                            const float* __restrict__ kDx, const float* __restrict__ kDy,
                            const float* __restrict__ bng,  const float* __restrict__ bng1,
                            const float* __restrict__ bnDx, const float* __restrict__ bnDy,
                            const float* __restrict__ bn_out,
                            float* __restrict__ wf) {
    const int t = threadIdx.x;        // 256 threads
    const int c = t & 63;
    const int q = t >> 6;             // which conv (0..3)
    const float* K = (q == 0) ? kg  : (q == 1) ? kg1  : (q == 2) ? kDx  : kDy;
    const float* P = (q == 0) ? bng : (q == 1) ? bng1 : (q == 2) ? bnDx : bnDy;
    const float ga = P[c], be = P[64 + c], mu = P[128 + c], va = P[192 + c];
    const float s = ga * rsqrtf(va + 1e-3f);
    const float b = be - mu * s;
    for (int k = 0; k < 9; ++k)
        wf[q * 576 + k * 64 + c] = K[k * 64 + c] * s;
    wf[OFF_BIAS + q * 64 + c] = b;
    if (q == 0) {
        const float ga2 = bn_out[c], be2 = bn_out[64 + c], mu2 = bn_out[128 + c], va2 = bn_out[192 + c];
        const float s2 = ga2 * rsqrtf(va2 + 1e-3f);
        wf[OFF_SO + c] = s2;
        wf[OFF_BO + c] = be2 - mu2 * s2;
    }
}

// ---------------- main fused kernel ---------------------------------------
__global__ __launch_bounds__(BS)
void diffusion_main(
    const float* __restrict__ s0, const float* __restrict__ wf,
    float* __restrict__ out)
{
    __shared__ float Lg[WW * LSTR];   // 43 KB: g row (for W-axis neighbors of g)
    __shared__ float Lh[WW * LSTR];   // 43 KB: h row (for W-axis neighbors of h)

    const int t    = threadIdx.x;
    const int w    = t >> 3;          // 0..127
    const int g    = t & 7;           // 8-channel group
    const int cb   = g * 8;           // base channel
    const int lane = t & 63;          // (w&7)*8 + g
    const int bid  = blockIdx.x;
    const int row  = ((bid & 7) << 8) | (bid >> 3);   // XCD-contiguous rows for L2 halo reuse
    const int h    = row & (HH - 1);
    const long rowbase = (long)row * (WW * CC);

    // conv accumulators initialized with folded BN bias
    F8 ag  = ld8(wf + OFF_BIAS + 0 * 64 + cb);
    F8 ag1 = ld8(wf + OFF_BIAS + 1 * 64 + cb);
    F8 adx = ld8(wf + OFF_BIAS + 2 * 64 + cb);
    F8 ady = ld8(wf + OFF_BIAS + 3 * 64 + cb);
    F8 f   = zero8();

    #pragma unroll
    for (int dh = -1; dh <= 1; ++dh) {
        const int h2 = h + dh;
        if (h2 < 0 || h2 >= HH) continue;             // block-uniform
        const float* rp = s0 + rowbase + (long)dh * (WW * CC);
        #pragma unroll
        for (int dw = -1; dw <= 1; ++dw) {
            const int w2 = w + dw;
            F8 v = ((unsigned)w2 < WW) ? ld8(rp + w2 * CC + cb) : zero8();
            const int k = (dh + 1) * 3 + (dw + 1);    // compile-time after unroll
            fma8(ag,  v, ld8(wf + OFF_WG  + k * 64 + cb));
            fma8(ag1, v, ld8(wf + OFF_WG1 + k * 64 + cb));
            fma8(adx, v, ld8(wf + OFF_WDX + k * 64 + cb));
            fma8(ady, v, ld8(wf + OFF_WDY + k * 64 + cb));
            if (dh == 0 && dw == 0) f = v;
        }
    }
    const F8 gg = relu8(ag);
    const F8 g1 = relu8(ag1);
    const F8 bx = scale8(relu8(adx), DTC);            // Bx = Dx*dt
    const F8 by = scale8(relu8(ady), DTC);            // By = Dy*dt

    st8(Lg + w * LSTR + cb, gg);
    st8(Lh + w * LSTR + cb, f);                       // h starts as f
    __syncthreads();

    const int wm = (w + WW - 1) & (WW - 1);
    const int wp = (w + 1) & (WW - 1);
    const int lm = (g == 0) ? lane + 7 : lane - 1;    // src lane for channel cb-1 (wrap)
    const int lp = (g == 7) ? lane - 7 : lane + 1;    // src lane for channel cb+8 (wrap)

    // ---- loop-invariant PDE coefficients (h0 == f for K=2) ----
    F8 A0, cE, cWm, cWp, cCm, cCp;
    {
        const F8 gwm = ld8(Lg + wm * LSTR + cb);
        const F8 gwp = ld8(Lg + wp * LSTR + cb);
        const float em = __shfl(g1.hi.w, lm);         // g1[c-1] for element 0
        const float ep = __shfl(g1.lo.x, lp);         // g1[c+1] for element 7
        const F8 g1m = shr8(g1, em);
        const F8 g1p = shl8(g1, ep);
#define X(fld) { \
        const float ux = 0.5f * (gwm.fld - gwp.fld); \
        const float vy = 0.5f * (g1m.fld - g1p.fld); \
        const float E  = (ux + vy) * DTC; \
        const float bxv = bx.fld, byv = by.fld; \
        const float D  = __builtin_amdgcn_rcpf(1.0f + 2.f * bxv + 2.f * byv); \
        const float Ax = gg.fld * DTC; \
        const float Ay = g1.fld * DTC; \
        A0.fld  = D * f.fld * (1.f - 2.f * bxv - 2.f * byv + 2.f * DTC); \
        cE.fld  = -2.f * E * D; \
        cWm.fld = D * (2.f * bxv - Ax); \
        cWp.fld = D * (2.f * bxv + Ax); \
        cCm.fld = D * (2.f * byv - Ay); \
        cCp.fld = D * (2.f * byv + Ay); }
        F8_ALL(X)
#undef X
    }

    F8 hreg = f;

    // ---- PDE: K=2 steps ----
    #pragma unroll
    for (int it = 0; it < 2; ++it) {
        const F8 hwm = ld8(Lh + wm * LSTR + cb);
        const F8 hwp = ld8(Lh + wp * LSTR + cb);
        const float em = __shfl(hreg.hi.w, lm);
        const float ep = __shfl(hreg.lo.x, lp);
        const F8 hcm = shr8(hreg, em);
        const F8 hcp = shl8(hreg, ep);
        F8 hn;
#define X(fld) { \
        float acc = A0.fld; \
        acc = fmaf(cE.fld,  hreg.fld, acc); \
        acc = fmaf(cWm.fld, hwm.fld,  acc); \
        acc = fmaf(cWp.fld, hwp.fld,  acc); \
        acc = fmaf(cCm.fld, hcm.fld,  acc); \
        acc = fmaf(cCp.fld, hcp.fld,  acc); \
        hn.fld = acc; }
        F8_ALL(X)
#undef X
        __syncthreads();                              // all Lh reads done
        st8(Lh + w * LSTR + cb, hn);
        hreg = hn;
        __syncthreads();                              // writes visible
    }

    // ---- epilogue: BN + ReLU ----
    {
        const F8 so = ld8(wf + OFF_SO + cb);
        const F8 bo = ld8(wf + OFF_BO + cb);
        F8 o;
#define X(fld) o.fld = fmaxf(fmaf(hreg.fld, so.fld, bo.fld), 0.f);
        F8_ALL(X)
#undef X
        st8(out + rowbase + w * CC + cb, o);
    }
}

extern "C" void kernel_launch(void* const* d_in, const int* in_sizes, int n_in,
                              void* d_out, int out_size, void* d_ws, size_t ws_size,
                              hipStream_t stream) {
    const float* s0   = (const float*)d_in[0];
    const float* kg   = (const float*)d_in[1];
    const float* kg1  = (const float*)d_in[2];
    const float* kDx  = (const float*)d_in[3];
    const float* kDy  = (const float*)d_in[4];
    const float* bng  = (const float*)d_in[5];
    const float* bng1 = (const float*)d_in[6];
    const float* bnDx = (const float*)d_in[7];
    const float* bnDy = (const float*)d_in[8];
    const float* bno  = (const float*)d_in[9];
    float* out = (float*)d_out;
    float* wf  = (float*)d_ws;   // 2688 floats

    fold_params<<<1, 256, 0, stream>>>(kg, kg1, kDx, kDy,
                                       bng, bng1, bnDx, bnDy, bno, wf);
    diffusion_main<<<dim3(16 * 128), dim3(BS), 0, stream>>>(s0, wf, out);
}

// Round 5
// 264.709 us; speedup vs baseline: 1.3669x; 1.3669x over previous
//
#include <hip/hip_runtime.h>

#define HH 128
#define WW 128
#define CC 64
// LSTR=65: lane offsets (w*65 + g*8) spread b128 start-banks with only 2-way
// aliasing (free, m136). LDS total = 2*128*65*4 + 10752 = 77312 B -> 2
// blocks/CU (155KB <= 160KB).
#define LSTR 65
#define BS 1024
#define DTC 0.2f

// float offsets into folded-param block (workspace AND its LDS copy)
#define OFF_WG   0
#define OFF_WG1  576
#define OFF_WDX  1152
#define OFF_WDY  1728
#define OFF_BIAS 2304    // [4][64]
#define OFF_SO   2560
#define OFF_BO   2624
#define WS_FLOATS 2688

struct F8 { float4 lo, hi; };

__device__ __forceinline__ F8 ld8(const float* p) {
    F8 r; r.lo = *(const float4*)p; r.hi = *(const float4*)(p + 4); return r;
}
__device__ __forceinline__ void st8(float* p, const F8& v) {
    *(float4*)p = v.lo; *(float4*)(p + 4) = v.hi;
}
__device__ __forceinline__ F8 zero8() {
    F8 r; r.lo = make_float4(0.f,0.f,0.f,0.f); r.hi = r.lo; return r;
}

#define F8_ALL(X) X(lo.x) X(lo.y) X(lo.z) X(lo.w) X(hi.x) X(hi.y) X(hi.z) X(hi.w)

__device__ __forceinline__ void fma8(F8& a, const F8& v, const F8& w) {
#define X(f) a.f = fmaf(v.f, w.f, a.f);
    F8_ALL(X)
#undef X
}
__device__ __forceinline__ F8 relu8(const F8& v) {
    F8 r;
#define X(f) r.f = fmaxf(v.f, 0.f);
    F8_ALL(X)
#undef X
    return r;
}
__device__ __forceinline__ F8 scale8(const F8& v, float s) {
    F8 r;
#define X(f) r.f = v.f * s;
    F8_ALL(X)
#undef X
    return r;
}
// result[i] = v[i-1]; result[0] = edge  (channel roll +1)
__device__ __forceinline__ F8 shr8(const F8& v, float edge) {
    F8 r;
    r.lo.x = edge;   r.lo.y = v.lo.x; r.lo.z = v.lo.y; r.lo.w = v.lo.z;
    r.hi.x = v.lo.w; r.hi.y = v.hi.x; r.hi.z = v.hi.y; r.hi.w = v.hi.z;
    return r;
}
// result[i] = v[i+1]; result[7] = edge  (channel roll -1)
__device__ __forceinline__ F8 shl8(const F8& v, float edge) {
    F8 r;
    r.lo.x = v.lo.y; r.lo.y = v.lo.z; r.lo.z = v.lo.w; r.lo.w = v.hi.x;
    r.hi.x = v.hi.y; r.hi.y = v.hi.z; r.hi.z = v.hi.w; r.hi.w = edge;
    return r;
}

// ---------------- pre-kernel: fold BN into conv weights -------------------
__global__ void fold_params(const float* __restrict__ kg,  const float* __restrict__ kg1,
                            const float* __restrict__ kDx, const float* __restrict__ kDy,
                            const float* __restrict__ bng,  const float* __restrict__ bng1,
                            const float* __restrict__ bnDx, const float* __restrict__ bnDy,
                            const float* __restrict__ bn_out,
                            float* __restrict__ wf) {
    const int t = threadIdx.x;        // 256 threads
    const int c = t & 63;
    const int q = t >> 6;             // which conv (0..3)
    const float* K = (q == 0) ? kg  : (q == 1) ? kg1  : (q == 2) ? kDx  : kDy;
    const float* P = (q == 0) ? bng : (q == 1) ? bng1 : (q == 2) ? bnDx : bnDy;
    const float ga = P[c], be = P[64 + c], mu = P[128 + c], va = P[192 + c];
    const float s = ga * rsqrtf(va + 1e-3f);
    const float b = be - mu * s;
    for (int k = 0; k < 9; ++k)
        wf[q * 576 + k * 64 + c] = K[k * 64 + c] * s;
    wf[OFF_BIAS + q * 64 + c] = b;
    if (q == 0) {
        const float ga2 = bn_out[c], be2 = bn_out[64 + c], mu2 = bn_out[128 + c], va2 = bn_out[192 + c];
        const float s2 = ga2 * rsqrtf(va2 + 1e-3f);
        wf[OFF_SO + c] = s2;
        wf[OFF_BO + c] = be2 - mu2 * s2;
    }
}

// ---------------- main fused kernel ---------------------------------------
__global__ __launch_bounds__(BS)
void diffusion_main(
    const float* __restrict__ s0, const float* __restrict__ wf,
    float* __restrict__ out)
{
    __shared__ float Lw[WS_FLOATS];   // 10.5 KB: folded weights/bias/out-BN
    __shared__ float Lg[WW * LSTR];   // 32.5 KB: g row (W-axis neighbors)
    __shared__ float Lh[WW * LSTR];   // 32.5 KB: h row (W-axis neighbors)

    const int t    = threadIdx.x;
    const int w    = t >> 3;          // 0..127
    const int g    = t & 7;           // 8-channel group
    const int cb   = g * 8;           // base channel
    const int lane = t & 63;          // (w&7)*8 + g
    const int bid  = blockIdx.x;
    const int row  = ((bid & 7) << 8) | (bid >> 3);   // XCD-contiguous rows for L2 halo reuse
    const int h    = row & (HH - 1);
    const long rowbase = (long)row * (WW * CC);

    // stage folded params global -> LDS (weight reads become cheap broadcast
    // ds_read_b128; keeps 36 long-latency global loads out of the conv loop,
    // which was hoist-spilling ~35 floats/thread to scratch -> 271MB HBM wr)
    for (int i = t; i < WS_FLOATS; i += BS) Lw[i] = wf[i];
    __syncthreads();

    // conv accumulators initialized with folded BN bias
    F8 ag  = ld8(Lw + OFF_BIAS + 0 * 64 + cb);
    F8 ag1 = ld8(Lw + OFF_BIAS + 1 * 64 + cb);
    F8 adx = ld8(Lw + OFF_BIAS + 2 * 64 + cb);
    F8 ady = ld8(Lw + OFF_BIAS + 3 * 64 + cb);
    F8 f   = zero8();

    #pragma unroll
    for (int dh = -1; dh <= 1; ++dh) {
        const int h2 = h + dh;
        if (h2 >= 0 && h2 < HH) {                     // block-uniform
            const float* rp = s0 + rowbase + (long)dh * (WW * CC);
            #pragma unroll
            for (int dw = -1; dw <= 1; ++dw) {
                const int w2 = w + dw;
                F8 v = ((unsigned)w2 < WW) ? ld8(rp + w2 * CC + cb) : zero8();
                const int k = (dh + 1) * 3 + (dw + 1);  // compile-time after unroll
                fma8(ag,  v, ld8(Lw + OFF_WG  + k * 64 + cb));
                fma8(ag1, v, ld8(Lw + OFF_WG1 + k * 64 + cb));
                fma8(adx, v, ld8(Lw + OFF_WDX + k * 64 + cb));
                fma8(ady, v, ld8(Lw + OFF_WDY + k * 64 + cb));
                if (dh == 0 && dw == 0) f = v;
            }
        }
        // pressure fence: keep at most one conv-row of loads in flight
        __builtin_amdgcn_sched_barrier(0);
    }
    const F8 gg = relu8(ag);
    const F8 g1 = relu8(ag1);
    const F8 bx = scale8(relu8(adx), DTC);            // Bx = Dx*dt
    const F8 by = scale8(relu8(ady), DTC);            // By = Dy*dt

    st8(Lg + w * LSTR + cb, gg);
    st8(Lh + w * LSTR + cb, f);                       // h starts as f
    __syncthreads();

    const int wm = (w + WW - 1) & (WW - 1);
    const int wp = (w + 1) & (WW - 1);
    const int lm = (g == 0) ? lane + 7 : lane - 1;    // src lane for channel cb-1 (wrap)
    const int lp = (g == 7) ? lane - 7 : lane + 1;    // src lane for channel cb+8 (wrap)

    // ---- loop-invariant PDE coefficients (h0 == f for K=2) ----
    F8 A0, cE, cWm, cWp, cCm, cCp;
    {
        const F8 gwm = ld8(Lg + wm * LSTR + cb);
        const F8 gwp = ld8(Lg + wp * LSTR + cb);
        const float em = __shfl(g1.hi.w, lm);         // g1[c-1] for element 0
        const float ep = __shfl(g1.lo.x, lp);         // g1[c+1] for element 7
        const F8 g1m = shr8(g1, em);
        const F8 g1p = shl8(g1, ep);
#define X(fld) { \
        const float ux = 0.5f * (gwm.fld - gwp.fld); \
        const float vy = 0.5f * (g1m.fld - g1p.fld); \
        const float E  = (ux + vy) * DTC; \
        const float bxv = bx.fld, byv = by.fld; \
        const float D  = __builtin_amdgcn_rcpf(1.0f + 2.f * bxv + 2.f * byv); \
        const float Ax = gg.fld * DTC; \
        const float Ay = g1.fld * DTC; \
        A0.fld  = D * f.fld * (1.f - 2.f * bxv - 2.f * byv + 2.f * DTC); \
        cE.fld  = -2.f * E * D; \
        cWm.fld = D * (2.f * bxv - Ax); \
        cWp.fld = D * (2.f * bxv + Ax); \
        cCm.fld = D * (2.f * byv - Ay); \
        cCp.fld = D * (2.f * byv + Ay); }
        F8_ALL(X)
#undef X
    }
    __builtin_amdgcn_sched_barrier(0);

    F8 hreg = f;

    // ---- PDE: K=2 steps ----
    #pragma unroll
    for (int it = 0; it < 2; ++it) {
        const F8 hwm = ld8(Lh + wm * LSTR + cb);
        const F8 hwp = ld8(Lh + wp * LSTR + cb);
        const float em = __shfl(hreg.hi.w, lm);
        const float ep = __shfl(hreg.lo.x, lp);
        const F8 hcm = shr8(hreg, em);
        const F8 hcp = shl8(hreg, ep);
        F8 hn;
#define X(fld) { \
        float acc = A0.fld; \
        acc = fmaf(cE.fld,  hreg.fld, acc); \
        acc = fmaf(cWm.fld, hwm.fld,  acc); \
        acc = fmaf(cWp.fld, hwp.fld,  acc); \
        acc = fmaf(cCm.fld, hcm.fld,  acc); \
        acc = fmaf(cCp.fld, hcp.fld,  acc); \
        hn.fld = acc; }
        F8_ALL(X)
#undef X
        __syncthreads();                              // all Lh reads done
        st8(Lh + w * LSTR + cb, hn);
        hreg = hn;
        __syncthreads();                              // writes visible
    }

    // ---- epilogue: BN + ReLU ----
    {
        const F8 so = ld8(Lw + OFF_SO + cb);
        const F8 bo = ld8(Lw + OFF_BO + cb);
        F8 o;
#define X(fld) o.fld = fmaxf(fmaf(hreg.fld, so.fld, bo.fld), 0.f);
        F8_ALL(X)
#undef X
        st8(out + rowbase + w * CC + cb, o);
    }
}

extern "C" void kernel_launch(void* const* d_in, const int* in_sizes, int n_in,
                              void* d_out, int out_size, void* d_ws, size_t ws_size,
                              hipStream_t stream) {
    const float* s0   = (const float*)d_in[0];
    const float* kg   = (const float*)d_in[1];
    const float* kg1  = (const float*)d_in[2];
    const float* kDx  = (const float*)d_in[3];
    const float* kDy  = (const float*)d_in[4];
    const float* bng  = (const float*)d_in[5];
    const float* bng1 = (const float*)d_in[6];
    const float* bnDx = (const float*)d_in[7];
    const float* bnDy = (const float*)d_in[8];
    const float* bno  = (const float*)d_in[9];
    float* out = (float*)d_out;
    float* wf  = (float*)d_ws;   // WS_FLOATS floats

    fold_params<<<1, 256, 0, stream>>>(kg, kg1, kDx, kDy,
                                       bng, bng1, bnDx, bnDy, bno, wf);
    diffusion_main<<<dim3(16 * 128), dim3(BS), 0, stream>>>(s0, wf, out);
}